// Round 15
// baseline (266.796 us; speedup 1.0000x reference)
//
#include <hip/hip_runtime.h>
#include <math.h>

#define DIM 512
#define NB 256
#define KMAX 12   // Taylor terms; k=13 tail ~2e-3 elementwise (Catalan growth checked)

using bf16x8 = __attribute__((ext_vector_type(8))) short;
using f32x4  = __attribute__((ext_vector_type(4))) float;
using float4v = __attribute__((ext_vector_type(4))) float;
using ushort4v = __attribute__((ext_vector_type(4))) unsigned short;

__device__ __forceinline__ unsigned short f2b(float f) {
    union { float f; unsigned int u; } v; v.f = f;
    unsigned int r = v.u + 0x7fffu + ((v.u >> 16) & 1u);
    return (unsigned short)(r >> 16);
}
__device__ __forceinline__ float b2f(unsigned short u) {
    union { unsigned int u; float f; } v; v.u = ((unsigned int)u) << 16;
    return v.f;
}
__device__ __forceinline__ ushort4v f2b4(float4v v) {
    ushort4v o;
    o.x = f2b(v.x); o.y = f2b(v.y); o.z = f2b(v.z); o.w = f2b(v.w);
    return o;
}

__device__ __forceinline__ void block_reduce2(float& s, float& q, float* sb1, float* sb2)
{
    int tid = threadIdx.x;
    #pragma unroll
    for (int off = 32; off > 0; off >>= 1) {
        s += __shfl_down(s, off);
        q += __shfl_down(q, off);
    }
    if ((tid & 63) == 0) { sb1[tid >> 6] = s; sb2[tid >> 6] = q; }
    __syncthreads();
    s = sb1[0] + sb1[1] + sb1[2] + sb1[3];
    q = sb2[0] + sb2[1] + sb2[2] + sb2[3];
    __syncthreads();
}

// ---------------------------------------------------------------------------
// Batched bf16 MFMA GEMM, BK=128, with on-the-fly fp32->bf16 staging.
// xf32/wf32: operand pointer is actually const float* (row-major, ld in f32
// elems); staged via registers + ds_write.  Otherwise bf16 via global_load_lds.
// acc: 0=store, 1=Cf+=, 2=atomicAdd(Cf).  Ct: transposed bf16 dual-write.
// Special blockIdx.y branches: lnd (LayerNorm/GELU/delta), pw (LSTM cell).
// ---------------------------------------------------------------------------
struct GemmDesc {
    const unsigned short* X;
    const unsigned short* W;
    const float* bias;
    float* Cf;
    unsigned short* Cb;
    unsigned short* Ct;
    int M, N, K, ldX, ldW, ldC, tr_row0, acc, xf32, wf32;
};
struct GemmArgs { GemmDesc d[10]; };
struct LnParams {
    const float* pre; const float* g; const float* beta;
    const float* w2; const float* b2; float* delta; float* coeff;
    int lnd_y;
};
struct PwParams {
    const float* gates; const float* bih; const float* bhh; const float* cin;
    const float* decays; float* hout; float* cout; unsigned short* combb;
    int pw_y;
};

__device__ __forceinline__ void stage_op(const unsigned short* Xp, int ld, int f32flag,
    int row, int schk, int kt, unsigned short* lptr, int bufi)
{
    if (f32flag) {
        const float* Xf = (const float*)Xp;
        const float* src = Xf + (size_t)row * ld + kt * 128 + schk * 8;
        #pragma unroll
        for (int hh = 0; hh < 4; ++hh) {
            float4v v0 = *(const float4v*)(src + hh * 32);
            float4v v1 = *(const float4v*)(src + hh * 32 + 4);
            unsigned short* d = lptr + bufi * 8192 + hh * 2048;
            *(ushort4v*)d       = f2b4(v0);
            *(ushort4v*)(d + 4) = f2b4(v1);
        }
    } else {
        const unsigned short* g = Xp + (size_t)row * ld + schk * 8;
        #pragma unroll
        for (int hh = 0; hh < 4; ++hh)
            __builtin_amdgcn_global_load_lds(
                (const __attribute__((address_space(1))) unsigned int*)(g + (size_t)kt * 128 + hh * 32),
                (__attribute__((address_space(3))) unsigned int*)(lptr + bufi * 8192 + hh * 2048), 16, 0, 0);
    }
}

__global__ __launch_bounds__(256) void gemm_mfma(GemmArgs args, LnParams lp, PwParams pp)
{
    __shared__ unsigned short lsA[2][8192];
    __shared__ unsigned short lsB[2][8192];
    __shared__ float sb1[4], sb2[4];

    if ((int)blockIdx.y == lp.lnd_y) {
        int b = blockIdx.x, tid = threadIdx.x;
        if (b >= 256) return;
        int i0 = tid, i1 = tid + 256;
        float x0 = lp.pre[(size_t)b * DIM + i0];
        float x1 = lp.pre[(size_t)b * DIM + i1];
        float s = x0 + x1, q = x0 * x0 + x1 * x1;
        block_reduce2(s, q, sb1, sb2);
        float mean = s * (1.f / DIM);
        float var  = q * (1.f / DIM) - mean * mean;
        float inv  = rsqrtf(var + 1e-5f);
        float y0 = (x0 - mean) * inv * lp.g[i0] + lp.beta[i0];
        float y1 = (x1 - mean) * inv * lp.g[i1] + lp.beta[i1];
        float h0 = 0.5f * y0 * (1.f + erff(y0 * 0.70710678118654752f));
        float h1 = 0.5f * y1 * (1.f + erff(y1 * 0.70710678118654752f));
        float p = h0 * lp.w2[i0] + h1 * lp.w2[i1];
        float dummy = 0.f;
        block_reduce2(p, dummy, sb1, sb2);
        if (tid == 0) {
            float z = p + lp.b2[0];
            float d = (z > 20.f) ? z : log1pf(expf(z));
            lp.delta[b] = d;
            float c = 1.f;
            lp.coeff[b] = 1.f;
            for (int k = 1; k <= KMAX; ++k) { c *= d / (float)k; lp.coeff[k * 256 + b] = c; }
        }
        return;
    }
    if ((int)blockIdx.y == pp.pw_y) {
        // LSTM cell: i2 over (s,b,d) = 3*256*512, vector x4
        int idx4 = blockIdx.x * 256 + threadIdx.x;
        if (idx4 >= 98304) return;
        int i2 = idx4 * 4;
        int s = i2 / (NB * DIM);
        int r = i2 - s * (NB * DIM);
        int b = r >> 9, d = r & 511;
        const float* gr = pp.gates + (size_t)s * 524288 + (size_t)b * 2048 + d;
        const float* bi = pp.bih + s * 2048 + d;
        const float* bh = pp.bhh + s * 2048 + d;
        float4v gi = *(const float4v*)(gr);
        float4v gf = *(const float4v*)(gr + 512);
        float4v gg = *(const float4v*)(gr + 1024);
        float4v go = *(const float4v*)(gr + 1536);
        float4v bi0 = *(const float4v*)(bi),        bh0 = *(const float4v*)(bh);
        float4v bi1 = *(const float4v*)(bi + 512),  bh1 = *(const float4v*)(bh + 512);
        float4v bi2 = *(const float4v*)(bi + 1024), bh2 = *(const float4v*)(bh + 1024);
        float4v bi3 = *(const float4v*)(bi + 1536), bh3 = *(const float4v*)(bh + 1536);
        float4v c = *(const float4v*)(pp.cin + i2);
        float dec = pp.decays[s];
        float4v hn, cn;
        #pragma unroll
        for (int j = 0; j < 4; ++j) {
            float vgi = ((const float*)&gi)[j] + ((const float*)&bi0)[j] + ((const float*)&bh0)[j];
            float vgf = ((const float*)&gf)[j] + ((const float*)&bi1)[j] + ((const float*)&bh1)[j];
            float vgg = ((const float*)&gg)[j] + ((const float*)&bi2)[j] + ((const float*)&bh2)[j];
            float vgo = ((const float*)&go)[j] + ((const float*)&bi3)[j] + ((const float*)&bh3)[j];
            float ig = 1.f / (1.f + expf(-vgi));
            float fg = 1.f / (1.f + expf(-vgf));
            float g_ = tanhf(vgg);
            float og = 1.f / (1.f + expf(-vgo));
            float cc = ((const float*)&c)[j];
            float craw = fg * cc + ig * g_;
            ((float*)&hn)[j] = og * tanhf(craw);
            ((float*)&cn)[j] = dec * cc + (1.f - dec) * craw;
        }
        *(float4v*)(pp.hout + i2) = hn;
        *(float4v*)(pp.cout + i2) = cn;
        *(ushort4v*)(pp.combb + (size_t)b * 2048 + 512 + s * 512 + d) = f2b4(hn);
        return;
    }

    GemmDesc de = args.d[blockIdx.y];
    int tn = de.N >> 6;
    int tiles = (de.M >> 6) * tn;
    int t = blockIdx.x;
    if (t >= tiles) return;
    int m0 = (t / tn) << 6;
    int n0 = (t % tn) << 6;

    int tid = threadIdx.x;
    int w = tid >> 6;
    int l = tid & 63;
    int nkt = de.K >> 7;      // BK=128

    int srow = w * 16 + (l >> 2);
    int schk = l & 3;
    unsigned short* lA = &lsA[0][(w * 64 + l) * 8];
    unsigned short* lB = &lsB[0][(w * 64 + l) * 8];

    int mbase = (w >> 1) * 32;
    int nbase = (w & 1) * 32;

    f32x4 acc[2][2];
    #pragma unroll
    for (int i = 0; i < 2; ++i)
        #pragma unroll
        for (int j = 0; j < 2; ++j)
            acc[i][j] = (f32x4){0.f, 0.f, 0.f, 0.f};

    int kg = l >> 4;
    int fr = l & 15;
    int aslot = (mbase * 4 + fr * 4 + kg) * 8;
    int bslot = (nbase * 4 + fr * 4 + kg) * 8;

    stage_op(de.X, de.ldX, de.xf32, m0 + srow, schk, 0, lA, 0);
    stage_op(de.W, de.ldW, de.wf32, n0 + srow, schk, 0, lB, 0);

    for (int kt = 0; kt < nkt; ++kt) {
        __syncthreads();
        if (kt + 1 < nkt) {
            stage_op(de.X, de.ldX, de.xf32, m0 + srow, schk, kt + 1, lA, (kt + 1) & 1);
            stage_op(de.W, de.ldW, de.wf32, n0 + srow, schk, kt + 1, lB, (kt + 1) & 1);
        }
        const unsigned short* bufA = &lsA[kt & 1][0];
        const unsigned short* bufB = &lsB[kt & 1][0];
        #pragma unroll
        for (int h = 0; h < 4; ++h) {
            bf16x8 a0 = *(const bf16x8*)(bufA + h * 2048 + aslot);
            bf16x8 a1 = *(const bf16x8*)(bufA + h * 2048 + aslot + 512);
            bf16x8 b0 = *(const bf16x8*)(bufB + h * 2048 + bslot);
            bf16x8 b1 = *(const bf16x8*)(bufB + h * 2048 + bslot + 512);
            acc[0][0] = __builtin_amdgcn_mfma_f32_16x16x32_bf16(a0, b0, acc[0][0], 0, 0, 0);
            acc[0][1] = __builtin_amdgcn_mfma_f32_16x16x32_bf16(a0, b1, acc[0][1], 0, 0, 0);
            acc[1][0] = __builtin_amdgcn_mfma_f32_16x16x32_bf16(a1, b0, acc[1][0], 0, 0, 0);
            acc[1][1] = __builtin_amdgcn_mfma_f32_16x16x32_bf16(a1, b1, acc[1][1], 0, 0, 0);
        }
        __syncthreads();   // writes for buf kt+1 must not pass reads of buf kt
    }

    #pragma unroll
    for (int mi = 0; mi < 2; ++mi) {
        #pragma unroll
        for (int ni = 0; ni < 2; ++ni) {
            int col = n0 + nbase + ni * 16 + fr;
            float bv = de.bias ? de.bias[col] : 0.f;
            #pragma unroll
            for (int r = 0; r < 4; ++r) {
                int row = m0 + mbase + mi * 16 + (l >> 4) * 4 + r;
                float v = acc[mi][ni][r] + bv;
                if (de.Cf) {
                    if (de.acc == 2)      atomicAdd(&de.Cf[(size_t)row * de.ldC + col], v);
                    else if (de.acc == 1) de.Cf[(size_t)row * de.ldC + col] += v;
                    else                  de.Cf[(size_t)row * de.ldC + col] = v;
                } else {
                    de.Cb[(size_t)row * de.ldC + col] = f2b(v);
                }
                if (de.Ct && row >= de.tr_row0)
                    de.Ct[(size_t)col * 512 + (row - de.tr_row0)] = f2b(v);
            }
        }
    }
}

// ---------------------------------------------------------------------------
// d1: A^T transpose (bf16) + zero gates + seed projout with proj_b.
// Grid 384 x 256: bid<256 transpose; else zero/seed.
// ---------------------------------------------------------------------------
__global__ __launch_bounds__(256) void prep0(
    const float* __restrict__ A, unsigned short* __restrict__ ATb,
    float* __restrict__ gates, const float* __restrict__ proj_b,
    float* __restrict__ projout)
{
    __shared__ float tile[32][33];
    int bid = blockIdx.x, tid = threadIdx.x;
    if (bid < 256) {
        int bx = bid & 15, by = bid >> 4;
        int tx = tid & 31, ty = tid >> 5;
        #pragma unroll
        for (int i = 0; i < 32; i += 8)
            tile[ty + i][tx] = A[(size_t)(by * 32 + ty + i) * 512 + bx * 32 + tx];
        __syncthreads();
        #pragma unroll
        for (int i = 0; i < 32; i += 8)
            ATb[(size_t)(bx * 32 + ty + i) * 512 + by * 32 + tx] = f2b(tile[tx][ty + i]);
    } else {
        // 128 blocks: zero gates (393216 f4) then seed projout (32768 f4)
        const int gstride = 128 * 256;
        int g0 = (bid - 256) * 256 + tid;
        float4v z = (float4v){0.f, 0.f, 0.f, 0.f};
        for (int i = g0; i < 393216; i += gstride)
            ((float4v*)gates)[i] = z;
        for (int i = g0; i < 32768; i += gstride) {
            float4v pb = *(const float4v*)(proj_b + (i & 127) * 4);
            ((float4v*)projout)[i] = pb;
        }
    }
}

// ---------------------------------------------------------------------------
// d7: hssm pointwise: hssm = h_prev + sum c_k T_k + delta*Bx; combb col0 bf16.
// Grid 128 x 256 (x4 vectorized).
// ---------------------------------------------------------------------------
__global__ __launch_bounds__(256) void pwh_kernel(
    const float* __restrict__ Tm, const float* __restrict__ coeff,
    const float* __restrict__ h_prev, const float* __restrict__ delta,
    const float* __restrict__ Bx, float* __restrict__ hssm,
    unsigned short* __restrict__ combb)
{
    int idx4 = blockIdx.x * 256 + threadIdx.x;   // 0..32767
    int base = idx4 * 4;
    int b = base >> 9, i = base & 511;
    const float* Tr = Tm + (size_t)b * (KMAX * DIM) + i;
    float4v a = *(const float4v*)(h_prev + base);
    #pragma unroll
    for (int k = 1; k <= KMAX; ++k) {
        float c = coeff[k * 256 + b];
        float4v t = *(const float4v*)(Tr + (size_t)(k - 1) * DIM);
        a.x += c * t.x; a.y += c * t.y; a.z += c * t.z; a.w += c * t.w;
    }
    float dl = delta[b];
    float4v bx = *(const float4v*)(Bx + base);
    a.x += dl * bx.x; a.y += dl * bx.y; a.z += dl * bx.z; a.w += dl * bx.w;
    *(float4v*)(hssm + base) = a;
    *(ushort4v*)(combb + (size_t)b * 2048 + i) = f2b4(a);
}

// ---------------------------------------------------------------------------
// d9: tail: attn + fused = ctx.aout_w^T + aout_b + out = LN(projA + fused.P2^T)
// aout_w / proj_w read as fp32.  One block per row b.
// ---------------------------------------------------------------------------
__global__ __launch_bounds__(256) void tail_kernel(
    const unsigned short* __restrict__ qb, const unsigned short* __restrict__ kvb,
    const float* __restrict__ aout_w, const float* __restrict__ aout_b,
    const float* __restrict__ proj_w, const float* __restrict__ projA,
    const float* __restrict__ fin_g, const float* __restrict__ fin_beta,
    float* __restrict__ outp)
{
    __shared__ float ctxs[512];
    __shared__ float fusedl[512];
    __shared__ float totals[512];
    __shared__ float sb1[4], sb2[4];
    int b = blockIdx.x, tid = threadIdx.x;

    if (tid < 128) {
        int h = tid >> 4, sub = (tid & 15) * 4;
        int col = h * 64 + sub;
        ushort4v q4 = *(const ushort4v*)(qb + (size_t)b * 512 + col);
        float qf[4] = { b2f(q4.x), b2f(q4.y), b2f(q4.z), b2f(q4.w) };
        float p[3];
        ushort4v k4[3], v4[3];
        #pragma unroll
        for (int s = 0; s < 3; ++s) {
            k4[s] = *(const ushort4v*)(kvb + (size_t)s * 262144 + (size_t)b * 1024 + col);
            v4[s] = *(const ushort4v*)(kvb + (size_t)s * 262144 + (size_t)b * 1024 + 512 + col);
            p[s] = qf[0] * b2f(k4[s].x) + qf[1] * b2f(k4[s].y)
                 + qf[2] * b2f(k4[s].z) + qf[3] * b2f(k4[s].w);
        }
        #pragma unroll
        for (int off = 1; off < 16; off <<= 1) {
            p[0] += __shfl_xor(p[0], off);
            p[1] += __shfl_xor(p[1], off);
            p[2] += __shfl_xor(p[2], off);
        }
        const float scale = 0.125f;
        float p0 = p[0] * scale, p1 = p[1] * scale, p2 = p[2] * scale;
        float m = fmaxf(p0, fmaxf(p1, p2));
        float w0 = expf(p0 - m), w1 = expf(p1 - m), w2 = expf(p2 - m);
        float invs = 1.f / (w0 + w1 + w2);
        ctxs[col + 0] = (w0 * b2f(v4[0].x) + w1 * b2f(v4[1].x) + w2 * b2f(v4[2].x)) * invs;
        ctxs[col + 1] = (w0 * b2f(v4[0].y) + w1 * b2f(v4[1].y) + w2 * b2f(v4[2].y)) * invs;
        ctxs[col + 2] = (w0 * b2f(v4[0].z) + w1 * b2f(v4[1].z) + w2 * b2f(v4[2].z)) * invs;
        ctxs[col + 3] = (w0 * b2f(v4[0].w) + w1 * b2f(v4[1].w) + w2 * b2f(v4[2].w)) * invs;
    }
    __syncthreads();

    for (int jj = tid; jj < 512; jj += 256) {
        float acc = aout_b[jj];
        const float* wr = aout_w + (size_t)jj * 512;
        for (int k = 0; k < 512; k += 8) {
            float4v w0 = *(const float4v*)(wr + k);
            float4v w1 = *(const float4v*)(wr + k + 4);
            acc += ctxs[k+0]*w0.x + ctxs[k+1]*w0.y + ctxs[k+2]*w0.z + ctxs[k+3]*w0.w
                 + ctxs[k+4]*w1.x + ctxs[k+5]*w1.y + ctxs[k+6]*w1.z + ctxs[k+7]*w1.w;
        }
        fusedl[jj] = acc;
    }
    __syncthreads();

    for (int ii = tid; ii < 512; ii += 256) {
        float acc = projA[(size_t)b * 512 + ii];
        const float* pr = proj_w + (size_t)ii * 2560 + 512;   // P2 (fused) slice
        for (int j = 0; j < 512; j += 8) {
            float4v w0 = *(const float4v*)(pr + j);
            float4v w1 = *(const float4v*)(pr + j + 4);
            acc += fusedl[j+0]*w0.x + fusedl[j+1]*w0.y + fusedl[j+2]*w0.z + fusedl[j+3]*w0.w
                 + fusedl[j+4]*w1.x + fusedl[j+5]*w1.y + fusedl[j+6]*w1.z + fusedl[j+7]*w1.w;
        }
        totals[ii] = acc;
    }
    __syncthreads();

    float x0 = totals[tid], x1 = totals[tid + 256];
    float s = x0 + x1, q = x0 * x0 + x1 * x1;
    block_reduce2(s, q, sb1, sb2);
    float mean = s * (1.f / DIM);
    float var  = q * (1.f / DIM) - mean * mean;
    float inv  = rsqrtf(var + 1e-5f);
    outp[(size_t)b * DIM + tid]       = (x0 - mean) * inv * fin_g[tid]       + fin_beta[tid];
    outp[(size_t)b * DIM + tid + 256] = (x1 - mean) * inv * fin_g[tid + 256] + fin_beta[tid + 256];
}

// ---------------------------------------------------------------------------
extern "C" void kernel_launch(void* const* d_in, const int* in_sizes, int n_in,
                              void* d_out, int out_size, void* d_ws, size_t ws_size,
                              hipStream_t stream)
{
    const float* x        = (const float*)d_in[0];
    const float* h_prev   = (const float*)d_in[1];
    const float* lstm_h   = (const float*)d_in[2];
    const float* lstm_c   = (const float*)d_in[3];
    const float* A        = (const float*)d_in[4];
    const float* Bm       = (const float*)d_in[5];
    const float* dn_w1    = (const float*)d_in[6];
    const float* dn_b1    = (const float*)d_in[7];
    const float* dn_g     = (const float*)d_in[8];
    const float* dn_beta  = (const float*)d_in[9];
    const float* dn_w2    = (const float*)d_in[10];
    const float* dn_b2    = (const float*)d_in[11];
    const float* wih      = (const float*)d_in[12];
    const float* whh      = (const float*)d_in[13];
    const float* bih      = (const float*)d_in[14];
    const float* bhh      = (const float*)d_in[15];
    const float* decays   = (const float*)d_in[16];
    const float* ain_w    = (const float*)d_in[17];
    const float* ain_b    = (const float*)d_in[18];
    const float* aout_w   = (const float*)d_in[19];
    const float* aout_b   = (const float*)d_in[20];
    const float* proj_w   = (const float*)d_in[21];
    const float* proj_b   = (const float*)d_in[22];
    const float* proj_g   = (const float*)d_in[23];
    const float* proj_bt  = (const float*)d_in[24];

    float* out  = (float*)d_out;
    float* hssm = out + 131072;
    float* hnew = out + 262144;
    float* cnew = out + 655360;

    // ---- workspace ----
    unsigned short* us = (unsigned short*)d_ws;
    unsigned short* ATb   = us;                    // 262144
    unsigned short* P     = us + 262144;           // 7*262144 [A^2..A^8]
    unsigned short* Qa    = us + 2097152;          // 262144  (A^2)^T
    unsigned short* Qb    = us + 2359296;          // 262144  (A^4)^T
    unsigned short* combb = us + 2621440;          // 524288 (256x2048) [hssm|hnew*3]
    unsigned short* qb    = us + 3145728;          // 131072
    unsigned short* kvb   = us + 3276800;          // 786432
    unsigned short* U8b   = us + 4063232;          // 131072
    float* fbase  = (float*)(us + 4194304);
    float* pre1    = fbase;                        // 131072
    float* delta   = fbase + 131072;               // 256
    float* coeff   = fbase + 131328;               // 13*256
    float* Bx      = fbase + 134656;               // 131072
    float* Tm      = fbase + 265728;               // 256*6144
    float* gates   = fbase + 1838592;              // 1572864
    float* projout = fbase + 3411456;              // 131072

    LnParams lpOff; lpOff.pre=nullptr; lpOff.g=nullptr; lpOff.beta=nullptr;
    lpOff.w2=nullptr; lpOff.b2=nullptr; lpOff.delta=nullptr; lpOff.coeff=nullptr; lpOff.lnd_y=-1;
    PwParams ppOff; ppOff.gates=nullptr; ppOff.bih=nullptr; ppOff.bhh=nullptr; ppOff.cin=nullptr;
    ppOff.decays=nullptr; ppOff.hout=nullptr; ppOff.cout=nullptr; ppOff.combb=nullptr; ppOff.pw_y=-1;

    #define US(p) ((const unsigned short*)(p))

    // ---- d1: A^T + zero gates + seed projout ----
    prep0<<<384, 256, 0, stream>>>(A, ATb, gates, proj_b, projout);

    GemmArgs ga;
    GemmDesc z0 = { nullptr,nullptr,nullptr,nullptr,nullptr,nullptr, 0,64,128,0,0,0,0,0,0,0 };
    for (int i = 0; i < 10; ++i) ga.d[i] = z0;

    // ---- d2: dense1, Bx, G1 (A^2+Q2), LSTM x6 (split, atomic) ----
    ga.d[0] = { US(x), US(dn_w1), dn_b1, pre1, nullptr, nullptr, 256,512,512, 512,512,512, 0,0, 1,1 };
    ga.d[1] = { US(x), US(Bm),   nullptr, Bx,  nullptr, nullptr, 256,512,512, 512,512,512, 0,0, 1,1 };
    ga.d[2] = { US(A), ATb,      nullptr, nullptr, P, Qa,        512,512,512, 512,512,512, 0,0, 1,0 };
    for (int s = 0; s < 3; ++s) {
        ga.d[3+s*2]   = { US(x), US(wih + (size_t)s*1048576), nullptr, gates + (size_t)s*524288,
                          nullptr, nullptr, 256,2048,512, 512,512,2048, 0,2, 1,1 };
        ga.d[4+s*2]   = { US(lstm_h + (size_t)s*131072), US(whh + (size_t)s*1048576), nullptr,
                          gates + (size_t)s*524288, nullptr, nullptr, 256,2048,512, 512,512,2048, 0,2, 1,1 };
    }
    gemm_mfma<<<dim3(128, 9), 256, 0, stream>>>(ga, lpOff, ppOff);

    // ---- d3: G2a (A^3), G2b (A^4 + Q4), lnd (y=2), pw-LSTM (y=3) ----
    for (int i = 0; i < 10; ++i) ga.d[i] = z0;
    ga.d[0] = { US(A), Qa, nullptr, nullptr, P + 1*262144, nullptr, 512,512,512, 512,512,512, 0,0, 1,0 };
    ga.d[1] = { P,     Qa, nullptr, nullptr, P + 2*262144, Qb,      512,512,512, 512,512,512, 0,0, 0,0 };
    LnParams lp1 = { pre1, dn_g, dn_beta, dn_w2, dn_b2, delta, coeff, 2 };
    PwParams pp1 = { gates, bih, bhh, lstm_c, decays, hnew, cnew, combb, 3 };
    gemm_mfma<<<dim3(384, 4), 256, 0, stream>>>(ga, lp1, pp1);

    // ---- d4: G3a (A^5), G3b (A^6..A^8), T1a (k1, k2..4), kv x3, projA-hnew x3 ----
    for (int i = 0; i < 10; ++i) ga.d[i] = z0;
    ga.d[0] = { US(A), Qb, nullptr, nullptr, P + 3*262144, nullptr, 512,512,512, 512,512,512, 0,0, 1,0 };
    ga.d[1] = { P,     Qb, nullptr, nullptr, P + 4*262144, nullptr, 1536,512,512, 512,512,512, 0,0, 0,0 };
    ga.d[2] = { US(h_prev), US(A), nullptr, Tm,       nullptr, nullptr, 256,512,512,  512,512,6144, 0,0, 1,1 };
    ga.d[3] = { US(h_prev), P,     nullptr, Tm + 512, nullptr, nullptr, 256,1536,512, 512,512,6144, 0,0, 1,0 };
    for (int s = 0; s < 3; ++s) {
        ga.d[4+s] = { combb + 512 + (size_t)s*512, US(ain_w + 262144), ain_b + 512,
                      nullptr, kvb + (size_t)s*262144, nullptr, 256,1024,512, 2048,512,1024, 0,0, 0,1 };
        ga.d[7+s] = { combb + 512 + (size_t)s*512, US(proj_w + 1024 + (size_t)s*512), nullptr,
                      projout, nullptr, nullptr, 256,512,512, 2048,2560,512, 0,2, 0,1 };
    }
    gemm_mfma<<<dim3(192, 10), 256, 0, stream>>>(ga, lpOff, ppOff);

    // ---- d5: T1b (k5..8) + U8 = bf16(A^8 h) ----
    for (int i = 0; i < 10; ++i) ga.d[i] = z0;
    ga.d[0] = { US(h_prev), P + 3*262144, nullptr, Tm + 4*512, nullptr, nullptr, 256,2048,512, 512,512,6144, 0,0, 1,0 };
    ga.d[1] = { US(h_prev), P + 6*262144, nullptr, nullptr, U8b, nullptr, 256,512,512, 512,512,512, 0,0, 1,0 };
    gemm_mfma<<<dim3(128, 2), 256, 0, stream>>>(ga, lpOff, ppOff);

    // ---- d6: T2a (k9: W=A), T2b (k10..12: W=A^2..A^4) ----
    for (int i = 0; i < 10; ++i) ga.d[i] = z0;
    ga.d[0] = { U8b, US(A), nullptr, Tm + 8*512, nullptr, nullptr, 256,512,512,  512,512,6144, 0,0, 0,1 };
    ga.d[1] = { U8b, P,     nullptr, Tm + 9*512, nullptr, nullptr, 256,1536,512, 512,512,6144, 0,0, 0,0 };
    gemm_mfma<<<dim3(96, 2), 256, 0, stream>>>(ga, lpOff, ppOff);

    // ---- d7: hssm pointwise ----
    pwh_kernel<<<128, 256, 0, stream>>>(Tm, coeff, h_prev, delta, Bx, hssm, combb);

    // ---- d8: q + projA-hssm (atomic) ----
    for (int i = 0; i < 10; ++i) ga.d[i] = z0;
    ga.d[0] = { combb, US(ain_w),  ain_b,  nullptr, qb, nullptr, 256,512,512, 2048,512,512, 0,0, 0,1 };
    ga.d[1] = { combb, US(proj_w), nullptr, projout, nullptr, nullptr, 256,512,512, 2048,2560,512, 0,2, 0,1 };
    gemm_mfma<<<dim3(32, 2), 256, 0, stream>>>(ga, lpOff, ppOff);

    // ---- d9: tail (attn + out-proj + P2 + final LN) ----
    tail_kernel<<<256, 256, 0, stream>>>(qb, kvb, aout_w, aout_b, proj_w, projout,
                                         proj_g, proj_bt, out);
    #undef US
}

// Round 16
// 264.173 us; speedup vs baseline: 1.0099x; 1.0099x over previous
//
#include <hip/hip_runtime.h>
#include <math.h>

#define DIM 512
#define NB 256
#define KMAX 12   // Taylor terms; k=13 tail ~2e-3 elementwise (Catalan growth checked)

using bf16x8 = __attribute__((ext_vector_type(8))) short;
using f32x4  = __attribute__((ext_vector_type(4))) float;
using float4v = __attribute__((ext_vector_type(4))) float;
using ushort4v = __attribute__((ext_vector_type(4))) unsigned short;

__device__ __forceinline__ unsigned short f2b(float f) {
    union { float f; unsigned int u; } v; v.f = f;
    unsigned int r = v.u + 0x7fffu + ((v.u >> 16) & 1u);
    return (unsigned short)(r >> 16);
}
__device__ __forceinline__ float b2f(unsigned short u) {
    union { unsigned int u; float f; } v; v.u = ((unsigned int)u) << 16;
    return v.f;
}
__device__ __forceinline__ ushort4v f2b4(float4v v) {
    ushort4v o;
    o.x = f2b(v.x); o.y = f2b(v.y); o.z = f2b(v.z); o.w = f2b(v.w);
    return o;
}

__device__ __forceinline__ void block_reduce2(float& s, float& q, float* sb1, float* sb2)
{
    int tid = threadIdx.x;
    #pragma unroll
    for (int off = 32; off > 0; off >>= 1) {
        s += __shfl_down(s, off);
        q += __shfl_down(q, off);
    }
    if ((tid & 63) == 0) { sb1[tid >> 6] = s; sb2[tid >> 6] = q; }
    __syncthreads();
    s = sb1[0] + sb1[1] + sb1[2] + sb1[3];
    q = sb2[0] + sb2[1] + sb2[2] + sb2[3];
    __syncthreads();
}

// ---------------------------------------------------------------------------
// Batched bf16 MFMA GEMM, BK=128, with on-the-fly fp32->bf16 staging.
// xf32/wf32: operand pointer is actually const float*.  acc: 0=store, 1=+=,
// 2=atomicAdd.  Ct: transposed bf16 dual-write.  y-branches: lnd, pw(LSTM).
// ---------------------------------------------------------------------------
struct GemmDesc {
    const unsigned short* X;
    const unsigned short* W;
    const float* bias;
    float* Cf;
    unsigned short* Cb;
    unsigned short* Ct;
    int M, N, K, ldX, ldW, ldC, tr_row0, acc, xf32, wf32;
};
struct GemmArgs { GemmDesc d[10]; };
struct LnParams {
    const float* pre; const float* g; const float* beta;
    const float* w2; const float* b2; float* delta; float* coeff;
    int lnd_y;
};
struct PwParams {
    const float* gates; const float* bih; const float* bhh; const float* cin;
    const float* decays; float* hout; float* cout; unsigned short* combb;
    int pw_y;
};

__device__ __forceinline__ void stage_op(const unsigned short* Xp, int ld, int f32flag,
    int row, int schk, int kt, unsigned short* lptr, int bufi)
{
    if (f32flag) {
        const float* Xf = (const float*)Xp;
        const float* src = Xf + (size_t)row * ld + kt * 128 + schk * 8;
        #pragma unroll
        for (int hh = 0; hh < 4; ++hh) {
            float4v v0 = *(const float4v*)(src + hh * 32);
            float4v v1 = *(const float4v*)(src + hh * 32 + 4);
            unsigned short* d = lptr + bufi * 8192 + hh * 2048;
            *(ushort4v*)d       = f2b4(v0);
            *(ushort4v*)(d + 4) = f2b4(v1);
        }
    } else {
        const unsigned short* g = Xp + (size_t)row * ld + schk * 8;
        #pragma unroll
        for (int hh = 0; hh < 4; ++hh)
            __builtin_amdgcn_global_load_lds(
                (const __attribute__((address_space(1))) unsigned int*)(g + (size_t)kt * 128 + hh * 32),
                (__attribute__((address_space(3))) unsigned int*)(lptr + bufi * 8192 + hh * 2048), 16, 0, 0);
    }
}

__global__ __launch_bounds__(256) void gemm_mfma(GemmArgs args, LnParams lp, PwParams pp)
{
    __shared__ unsigned short lsA[2][8192];
    __shared__ unsigned short lsB[2][8192];
    __shared__ float sb1[4], sb2[4];

    if ((int)blockIdx.y == lp.lnd_y) {
        int b = blockIdx.x, tid = threadIdx.x;
        if (b >= 256) return;
        int i0 = tid, i1 = tid + 256;
        float x0 = lp.pre[(size_t)b * DIM + i0];
        float x1 = lp.pre[(size_t)b * DIM + i1];
        float s = x0 + x1, q = x0 * x0 + x1 * x1;
        block_reduce2(s, q, sb1, sb2);
        float mean = s * (1.f / DIM);
        float var  = q * (1.f / DIM) - mean * mean;
        float inv  = rsqrtf(var + 1e-5f);
        float y0 = (x0 - mean) * inv * lp.g[i0] + lp.beta[i0];
        float y1 = (x1 - mean) * inv * lp.g[i1] + lp.beta[i1];
        float h0 = 0.5f * y0 * (1.f + erff(y0 * 0.70710678118654752f));
        float h1 = 0.5f * y1 * (1.f + erff(y1 * 0.70710678118654752f));
        float p = h0 * lp.w2[i0] + h1 * lp.w2[i1];
        float dummy = 0.f;
        block_reduce2(p, dummy, sb1, sb2);
        if (tid == 0) {
            float z = p + lp.b2[0];
            float d = (z > 20.f) ? z : log1pf(expf(z));
            lp.delta[b] = d;
            float c = 1.f;
            lp.coeff[b] = 1.f;
            for (int k = 1; k <= KMAX; ++k) { c *= d / (float)k; lp.coeff[k * 256 + b] = c; }
        }
        return;
    }
    if ((int)blockIdx.y == pp.pw_y) {
        int idx4 = blockIdx.x * 256 + threadIdx.x;
        if (idx4 >= 98304) return;
        int i2 = idx4 * 4;
        int s = i2 / (NB * DIM);
        int r = i2 - s * (NB * DIM);
        int b = r >> 9, d = r & 511;
        const float* gr = pp.gates + (size_t)s * 524288 + (size_t)b * 2048 + d;
        const float* bi = pp.bih + s * 2048 + d;
        const float* bh = pp.bhh + s * 2048 + d;
        float4v gi = *(const float4v*)(gr);
        float4v gf = *(const float4v*)(gr + 512);
        float4v gg = *(const float4v*)(gr + 1024);
        float4v go = *(const float4v*)(gr + 1536);
        float4v bi0 = *(const float4v*)(bi),        bh0 = *(const float4v*)(bh);
        float4v bi1 = *(const float4v*)(bi + 512),  bh1 = *(const float4v*)(bh + 512);
        float4v bi2 = *(const float4v*)(bi + 1024), bh2 = *(const float4v*)(bh + 1024);
        float4v bi3 = *(const float4v*)(bi + 1536), bh3 = *(const float4v*)(bh + 1536);
        float4v c = *(const float4v*)(pp.cin + i2);
        float dec = pp.decays[s];
        float4v hn, cn;
        #pragma unroll
        for (int j = 0; j < 4; ++j) {
            float vgi = ((const float*)&gi)[j] + ((const float*)&bi0)[j] + ((const float*)&bh0)[j];
            float vgf = ((const float*)&gf)[j] + ((const float*)&bi1)[j] + ((const float*)&bh1)[j];
            float vgg = ((const float*)&gg)[j] + ((const float*)&bi2)[j] + ((const float*)&bh2)[j];
            float vgo = ((const float*)&go)[j] + ((const float*)&bi3)[j] + ((const float*)&bh3)[j];
            float ig = 1.f / (1.f + expf(-vgi));
            float fg = 1.f / (1.f + expf(-vgf));
            float g_ = tanhf(vgg);
            float og = 1.f / (1.f + expf(-vgo));
            float cc = ((const float*)&c)[j];
            float craw = fg * cc + ig * g_;
            ((float*)&hn)[j] = og * tanhf(craw);
            ((float*)&cn)[j] = dec * cc + (1.f - dec) * craw;
        }
        *(float4v*)(pp.hout + i2) = hn;
        *(float4v*)(pp.cout + i2) = cn;
        *(ushort4v*)(pp.combb + (size_t)b * 2048 + 512 + s * 512 + d) = f2b4(hn);
        return;
    }

    GemmDesc de = args.d[blockIdx.y];
    int tn = de.N >> 6;
    int tiles = (de.M >> 6) * tn;
    int t = blockIdx.x;
    if (t >= tiles) return;
    int m0 = (t / tn) << 6;
    int n0 = (t % tn) << 6;

    int tid = threadIdx.x;
    int w = tid >> 6;
    int l = tid & 63;
    int nkt = de.K >> 7;

    int srow = w * 16 + (l >> 2);
    int schk = l & 3;
    unsigned short* lA = &lsA[0][(w * 64 + l) * 8];
    unsigned short* lB = &lsB[0][(w * 64 + l) * 8];

    int mbase = (w >> 1) * 32;
    int nbase = (w & 1) * 32;

    f32x4 acc[2][2];
    #pragma unroll
    for (int i = 0; i < 2; ++i)
        #pragma unroll
        for (int j = 0; j < 2; ++j)
            acc[i][j] = (f32x4){0.f, 0.f, 0.f, 0.f};

    int kg = l >> 4;
    int fr = l & 15;
    int aslot = (mbase * 4 + fr * 4 + kg) * 8;
    int bslot = (nbase * 4 + fr * 4 + kg) * 8;

    stage_op(de.X, de.ldX, de.xf32, m0 + srow, schk, 0, lA, 0);
    stage_op(de.W, de.ldW, de.wf32, n0 + srow, schk, 0, lB, 0);

    for (int kt = 0; kt < nkt; ++kt) {
        __syncthreads();
        if (kt + 1 < nkt) {
            stage_op(de.X, de.ldX, de.xf32, m0 + srow, schk, kt + 1, lA, (kt + 1) & 1);
            stage_op(de.W, de.ldW, de.wf32, n0 + srow, schk, kt + 1, lB, (kt + 1) & 1);
        }
        const unsigned short* bufA = &lsA[kt & 1][0];
        const unsigned short* bufB = &lsB[kt & 1][0];
        #pragma unroll
        for (int h = 0; h < 4; ++h) {
            bf16x8 a0 = *(const bf16x8*)(bufA + h * 2048 + aslot);
            bf16x8 a1 = *(const bf16x8*)(bufA + h * 2048 + aslot + 512);
            bf16x8 b0 = *(const bf16x8*)(bufB + h * 2048 + bslot);
            bf16x8 b1 = *(const bf16x8*)(bufB + h * 2048 + bslot + 512);
            acc[0][0] = __builtin_amdgcn_mfma_f32_16x16x32_bf16(a0, b0, acc[0][0], 0, 0, 0);
            acc[0][1] = __builtin_amdgcn_mfma_f32_16x16x32_bf16(a0, b1, acc[0][1], 0, 0, 0);
            acc[1][0] = __builtin_amdgcn_mfma_f32_16x16x32_bf16(a1, b0, acc[1][0], 0, 0, 0);
            acc[1][1] = __builtin_amdgcn_mfma_f32_16x16x32_bf16(a1, b1, acc[1][1], 0, 0, 0);
        }
        __syncthreads();
    }

    #pragma unroll
    for (int mi = 0; mi < 2; ++mi) {
        #pragma unroll
        for (int ni = 0; ni < 2; ++ni) {
            int col = n0 + nbase + ni * 16 + fr;
            float bv = de.bias ? de.bias[col] : 0.f;
            #pragma unroll
            for (int r = 0; r < 4; ++r) {
                int row = m0 + mbase + mi * 16 + (l >> 4) * 4 + r;
                float v = acc[mi][ni][r] + bv;
                if (de.Cf) {
                    if (de.acc == 2)      atomicAdd(&de.Cf[(size_t)row * de.ldC + col], v);
                    else if (de.acc == 1) de.Cf[(size_t)row * de.ldC + col] += v;
                    else                  de.Cf[(size_t)row * de.ldC + col] = v;
                } else {
                    de.Cb[(size_t)row * de.ldC + col] = f2b(v);
                }
                if (de.Ct && row >= de.tr_row0)
                    de.Ct[(size_t)col * 512 + (row - de.tr_row0)] = f2b(v);
            }
        }
    }
}

// ---------------------------------------------------------------------------
// d1: A^T transpose + zero gates + seed projout + bf16-pack row-loop weights
// (aout_w, Wq = ain_w rows 0:512, P0 = proj_w cols 0:512, P2 = cols 512:1024).
// Grid 640 x 256.
// ---------------------------------------------------------------------------
__global__ __launch_bounds__(256) void prep0(
    const float* __restrict__ A, unsigned short* __restrict__ ATb,
    float* __restrict__ gates, const float* __restrict__ proj_b,
    float* __restrict__ projout,
    const float* __restrict__ aout_w, unsigned short* __restrict__ aout_wb,
    const float* __restrict__ ain_w,  unsigned short* __restrict__ Wqb,
    const float* __restrict__ proj_w, unsigned short* __restrict__ P0b,
    unsigned short* __restrict__ P2b)
{
    __shared__ float tile[32][33];
    int bid = blockIdx.x, tid = threadIdx.x;
    if (bid < 256) {
        int bx = bid & 15, by = bid >> 4;
        int tx = tid & 31, ty = tid >> 5;
        #pragma unroll
        for (int i = 0; i < 32; i += 8)
            tile[ty + i][tx] = A[(size_t)(by * 32 + ty + i) * 512 + bx * 32 + tx];
        __syncthreads();
        #pragma unroll
        for (int i = 0; i < 32; i += 8)
            ATb[(size_t)(bx * 32 + ty + i) * 512 + by * 32 + tx] = f2b(tile[tx][ty + i]);
    } else if (bid < 384) {
        const int gstride = 128 * 256;
        int g0 = (bid - 256) * 256 + tid;
        float4v z = (float4v){0.f, 0.f, 0.f, 0.f};
        for (int i = g0; i < 393216; i += gstride)
            ((float4v*)gates)[i] = z;
        for (int i = g0; i < 32768; i += gstride) {
            float4v pb = *(const float4v*)(proj_b + (i & 127) * 4);
            ((float4v*)projout)[i] = pb;
        }
    } else {
        const int gstride = 256 * 256;
        int g0 = (bid - 384) * 256 + tid;
        for (int i = g0; i < 65536; i += gstride) {
            *(ushort4v*)(aout_wb + (size_t)i * 4) = f2b4(((const float4v*)aout_w)[i]);
            *(ushort4v*)(Wqb + (size_t)i * 4)     = f2b4(((const float4v*)ain_w)[i]);
            int row = i >> 7, c = i & 127;
            *(ushort4v*)(P0b + (size_t)i * 4) =
                f2b4(*(const float4v*)(proj_w + (size_t)row * 2560 + c * 4));
            *(ushort4v*)(P2b + (size_t)i * 4) =
                f2b4(*(const float4v*)(proj_w + (size_t)row * 2560 + 512 + c * 4));
        }
    }
}

// ---------------------------------------------------------------------------
// d7: per-row: hssm = h_prev + sum c_k T_k + delta*Bx  (-> hssm, combb);
// then q[b] = hssm.Wq^T + bq (bf16 out) and projout[b] += hssm.P0^T.
// One block per row b (256 blocks).
// ---------------------------------------------------------------------------
__global__ __launch_bounds__(256) void pwh2_kernel(
    const float* __restrict__ Tm, const float* __restrict__ coeff,
    const float* __restrict__ h_prev, const float* __restrict__ delta,
    const float* __restrict__ Bx, float* __restrict__ hssm,
    unsigned short* __restrict__ combb,
    const unsigned short* __restrict__ Wqb, const float* __restrict__ ain_b,
    const unsigned short* __restrict__ P0b,
    unsigned short* __restrict__ qb, float* __restrict__ projout)
{
    __shared__ float hs[512];
    int b = blockIdx.x, tid = threadIdx.x;
    float dl = delta[b];
    for (int ii = tid; ii < 512; ii += 256) {
        const float* Tr = Tm + (size_t)b * (KMAX * DIM) + ii;
        float a = h_prev[(size_t)b * 512 + ii];
        #pragma unroll
        for (int k = 1; k <= KMAX; ++k)
            a += coeff[k * 256 + b] * Tr[(size_t)(k - 1) * DIM];
        a += dl * Bx[(size_t)b * 512 + ii];
        hs[ii] = a;
        hssm[(size_t)b * 512 + ii] = a;
        combb[(size_t)b * 2048 + ii] = f2b(a);
    }
    __syncthreads();

    for (int jj = tid; jj < 512; jj += 256) {
        float aq = ain_b[jj];
        float ap = projout[(size_t)b * 512 + jj];
        const unsigned short* wq = Wqb + (size_t)jj * 512;
        const unsigned short* p0 = P0b + (size_t)jj * 512;
        for (int k = 0; k < 512; k += 8) {
            ushort4v q0 = *(const ushort4v*)(wq + k);
            ushort4v q1 = *(const ushort4v*)(wq + k + 4);
            ushort4v r0 = *(const ushort4v*)(p0 + k);
            ushort4v r1 = *(const ushort4v*)(p0 + k + 4);
            aq += hs[k+0]*b2f(q0.x) + hs[k+1]*b2f(q0.y) + hs[k+2]*b2f(q0.z) + hs[k+3]*b2f(q0.w)
                + hs[k+4]*b2f(q1.x) + hs[k+5]*b2f(q1.y) + hs[k+6]*b2f(q1.z) + hs[k+7]*b2f(q1.w);
            ap += hs[k+0]*b2f(r0.x) + hs[k+1]*b2f(r0.y) + hs[k+2]*b2f(r0.z) + hs[k+3]*b2f(r0.w)
                + hs[k+4]*b2f(r1.x) + hs[k+5]*b2f(r1.y) + hs[k+6]*b2f(r1.z) + hs[k+7]*b2f(r1.w);
        }
        qb[(size_t)b * 512 + jj] = f2b(aq);
        projout[(size_t)b * 512 + jj] = ap;
    }
}

// ---------------------------------------------------------------------------
// d8: tail: attn + fused = ctx.aout_w^T + aout_b + out = LN(projA + fused.P2^T)
// bf16 packed weights.  One block per row b.
// ---------------------------------------------------------------------------
__global__ __launch_bounds__(256) void tail_kernel(
    const unsigned short* __restrict__ qb, const unsigned short* __restrict__ kvb,
    const unsigned short* __restrict__ aout_wb, const float* __restrict__ aout_b,
    const unsigned short* __restrict__ P2b, const float* __restrict__ projA,
    const float* __restrict__ fin_g, const float* __restrict__ fin_beta,
    float* __restrict__ outp)
{
    __shared__ float ctxs[512];
    __shared__ float fusedl[512];
    __shared__ float totals[512];
    __shared__ float sb1[4], sb2[4];
    int b = blockIdx.x, tid = threadIdx.x;

    if (tid < 128) {
        int h = tid >> 4, sub = (tid & 15) * 4;
        int col = h * 64 + sub;
        ushort4v q4 = *(const ushort4v*)(qb + (size_t)b * 512 + col);
        float qf[4] = { b2f(q4.x), b2f(q4.y), b2f(q4.z), b2f(q4.w) };
        float p[3];
        ushort4v k4[3], v4[3];
        #pragma unroll
        for (int s = 0; s < 3; ++s) {
            k4[s] = *(const ushort4v*)(kvb + (size_t)s * 262144 + (size_t)b * 1024 + col);
            v4[s] = *(const ushort4v*)(kvb + (size_t)s * 262144 + (size_t)b * 1024 + 512 + col);
            p[s] = qf[0] * b2f(k4[s].x) + qf[1] * b2f(k4[s].y)
                 + qf[2] * b2f(k4[s].z) + qf[3] * b2f(k4[s].w);
        }
        #pragma unroll
        for (int off = 1; off < 16; off <<= 1) {
            p[0] += __shfl_xor(p[0], off);
            p[1] += __shfl_xor(p[1], off);
            p[2] += __shfl_xor(p[2], off);
        }
        const float scale = 0.125f;
        float p0 = p[0] * scale, p1 = p[1] * scale, p2 = p[2] * scale;
        float m = fmaxf(p0, fmaxf(p1, p2));
        float w0 = expf(p0 - m), w1 = expf(p1 - m), w2 = expf(p2 - m);
        float invs = 1.f / (w0 + w1 + w2);
        ctxs[col + 0] = (w0 * b2f(v4[0].x) + w1 * b2f(v4[1].x) + w2 * b2f(v4[2].x)) * invs;
        ctxs[col + 1] = (w0 * b2f(v4[0].y) + w1 * b2f(v4[1].y) + w2 * b2f(v4[2].y)) * invs;
        ctxs[col + 2] = (w0 * b2f(v4[0].z) + w1 * b2f(v4[1].z) + w2 * b2f(v4[2].z)) * invs;
        ctxs[col + 3] = (w0 * b2f(v4[0].w) + w1 * b2f(v4[1].w) + w2 * b2f(v4[2].w)) * invs;
    }
    __syncthreads();

    for (int jj = tid; jj < 512; jj += 256) {
        float acc = aout_b[jj];
        const unsigned short* wr = aout_wb + (size_t)jj * 512;
        for (int k = 0; k < 512; k += 8) {
            ushort4v w0 = *(const ushort4v*)(wr + k);
            ushort4v w1 = *(const ushort4v*)(wr + k + 4);
            acc += ctxs[k+0]*b2f(w0.x) + ctxs[k+1]*b2f(w0.y)
                 + ctxs[k+2]*b2f(w0.z) + ctxs[k+3]*b2f(w0.w)
                 + ctxs[k+4]*b2f(w1.x) + ctxs[k+5]*b2f(w1.y)
                 + ctxs[k+6]*b2f(w1.z) + ctxs[k+7]*b2f(w1.w);
        }
        fusedl[jj] = acc;
    }
    __syncthreads();

    for (int ii = tid; ii < 512; ii += 256) {
        float acc = projA[(size_t)b * 512 + ii];
        const unsigned short* pr = P2b + (size_t)ii * 512;
        for (int j = 0; j < 512; j += 8) {
            ushort4v w0 = *(const ushort4v*)(pr + j);
            ushort4v w1 = *(const ushort4v*)(pr + j + 4);
            acc += fusedl[j+0]*b2f(w0.x) + fusedl[j+1]*b2f(w0.y)
                 + fusedl[j+2]*b2f(w0.z) + fusedl[j+3]*b2f(w0.w)
                 + fusedl[j+4]*b2f(w1.x) + fusedl[j+5]*b2f(w1.y)
                 + fusedl[j+6]*b2f(w1.z) + fusedl[j+7]*b2f(w1.w);
        }
        totals[ii] = acc;
    }
    __syncthreads();

    float x0 = totals[tid], x1 = totals[tid + 256];
    float s = x0 + x1, q = x0 * x0 + x1 * x1;
    block_reduce2(s, q, sb1, sb2);
    float mean = s * (1.f / DIM);
    float var  = q * (1.f / DIM) - mean * mean;
    float inv  = rsqrtf(var + 1e-5f);
    outp[(size_t)b * DIM + tid]       = (x0 - mean) * inv * fin_g[tid]       + fin_beta[tid];
    outp[(size_t)b * DIM + tid + 256] = (x1 - mean) * inv * fin_g[tid + 256] + fin_beta[tid + 256];
}

// ---------------------------------------------------------------------------
extern "C" void kernel_launch(void* const* d_in, const int* in_sizes, int n_in,
                              void* d_out, int out_size, void* d_ws, size_t ws_size,
                              hipStream_t stream)
{
    const float* x        = (const float*)d_in[0];
    const float* h_prev   = (const float*)d_in[1];
    const float* lstm_h   = (const float*)d_in[2];
    const float* lstm_c   = (const float*)d_in[3];
    const float* A        = (const float*)d_in[4];
    const float* Bm       = (const float*)d_in[5];
    const float* dn_w1    = (const float*)d_in[6];
    const float* dn_b1    = (const float*)d_in[7];
    const float* dn_g     = (const float*)d_in[8];
    const float* dn_beta  = (const float*)d_in[9];
    const float* dn_w2    = (const float*)d_in[10];
    const float* dn_b2    = (const float*)d_in[11];
    const float* wih      = (const float*)d_in[12];
    const float* whh      = (const float*)d_in[13];
    const float* bih      = (const float*)d_in[14];
    const float* bhh      = (const float*)d_in[15];
    const float* decays   = (const float*)d_in[16];
    const float* ain_w    = (const float*)d_in[17];
    const float* ain_b    = (const float*)d_in[18];
    const float* aout_w   = (const float*)d_in[19];
    const float* aout_b   = (const float*)d_in[20];
    const float* proj_w   = (const float*)d_in[21];
    const float* proj_b   = (const float*)d_in[22];
    const float* proj_g   = (const float*)d_in[23];
    const float* proj_bt  = (const float*)d_in[24];

    float* out  = (float*)d_out;
    float* hssm = out + 131072;
    float* hnew = out + 262144;
    float* cnew = out + 655360;

    // ---- workspace ----
    unsigned short* us = (unsigned short*)d_ws;
    unsigned short* ATb     = us;                    // 262144
    unsigned short* P       = us + 262144;           // 7*262144 [A^2..A^8]
    unsigned short* Qa      = us + 2097152;          // 262144  (A^2)^T
    unsigned short* Qb      = us + 2359296;          // 262144  (A^4)^T
    unsigned short* combb   = us + 2621440;          // 524288 (256x2048) [hssm|hnew*3]
    unsigned short* qb      = us + 3145728;          // 131072
    unsigned short* kvb     = us + 3276800;          // 786432
    unsigned short* U8b     = us + 4063232;          // 131072
    unsigned short* aout_wb = us + 4194304;          // 262144
    unsigned short* Wqb     = us + 4456448;          // 262144
    unsigned short* P0b     = us + 4718592;          // 262144
    unsigned short* P2b     = us + 4980736;          // 262144
    float* fbase  = (float*)(us + 5242880);
    float* pre1    = fbase;                          // 131072
    float* delta   = fbase + 131072;                 // 256
    float* coeff   = fbase + 131328;                 // 13*256
    float* Bx      = fbase + 134656;                 // 131072
    float* Tm      = fbase + 265728;                 // 256*6144
    float* gates   = fbase + 1838592;                // 1572864
    float* projout = fbase + 3411456;                // 131072

    LnParams lpOff; lpOff.pre=nullptr; lpOff.g=nullptr; lpOff.beta=nullptr;
    lpOff.w2=nullptr; lpOff.b2=nullptr; lpOff.delta=nullptr; lpOff.coeff=nullptr; lpOff.lnd_y=-1;
    PwParams ppOff; ppOff.gates=nullptr; ppOff.bih=nullptr; ppOff.bhh=nullptr; ppOff.cin=nullptr;
    ppOff.decays=nullptr; ppOff.hout=nullptr; ppOff.cout=nullptr; ppOff.combb=nullptr; ppOff.pw_y=-1;

    #define US(p) ((const unsigned short*)(p))

    // ---- d1: A^T + zero gates + seed projout + bf16 packs ----
    prep0<<<640, 256, 0, stream>>>(A, ATb, gates, proj_b, projout,
                                   aout_w, aout_wb, ain_w, Wqb, proj_w, P0b, P2b);

    GemmArgs ga;
    GemmDesc z0 = { nullptr,nullptr,nullptr,nullptr,nullptr,nullptr, 0,64,128,0,0,0,0,0,0,0 };
    for (int i = 0; i < 10; ++i) ga.d[i] = z0;

    // ---- d2: dense1, Bx, G1 (A^2+Q2), LSTM x6 (split, atomic) ----
    ga.d[0] = { US(x), US(dn_w1), dn_b1, pre1, nullptr, nullptr, 256,512,512, 512,512,512, 0,0, 1,1 };
    ga.d[1] = { US(x), US(Bm),   nullptr, Bx,  nullptr, nullptr, 256,512,512, 512,512,512, 0,0, 1,1 };
    ga.d[2] = { US(A), ATb,      nullptr, nullptr, P, Qa,        512,512,512, 512,512,512, 0,0, 1,0 };
    for (int s = 0; s < 3; ++s) {
        ga.d[3+s*2] = { US(x), US(wih + (size_t)s*1048576), nullptr, gates + (size_t)s*524288,
                        nullptr, nullptr, 256,2048,512, 512,512,2048, 0,2, 1,1 };
        ga.d[4+s*2] = { US(lstm_h + (size_t)s*131072), US(whh + (size_t)s*1048576), nullptr,
                        gates + (size_t)s*524288, nullptr, nullptr, 256,2048,512, 512,512,2048, 0,2, 1,1 };
    }
    gemm_mfma<<<dim3(128, 9), 256, 0, stream>>>(ga, lpOff, ppOff);

    // ---- d3: G2a (A^3), G2b (A^4 + Q4), lnd (y=2), pw-LSTM (y=3) ----
    for (int i = 0; i < 10; ++i) ga.d[i] = z0;
    ga.d[0] = { US(A), Qa, nullptr, nullptr, P + 1*262144, nullptr, 512,512,512, 512,512,512, 0,0, 1,0 };
    ga.d[1] = { P,     Qa, nullptr, nullptr, P + 2*262144, Qb,      512,512,512, 512,512,512, 0,0, 0,0 };
    LnParams lp1 = { pre1, dn_g, dn_beta, dn_w2, dn_b2, delta, coeff, 2 };
    PwParams pp1 = { gates, bih, bhh, lstm_c, decays, hnew, cnew, combb, 3 };
    gemm_mfma<<<dim3(384, 4), 256, 0, stream>>>(ga, lp1, pp1);

    // ---- d4: G3a (A^5), G3b (A^6..A^8), T1a (k1, k2..4), kv x3, projA-hnew x3 ----
    for (int i = 0; i < 10; ++i) ga.d[i] = z0;
    ga.d[0] = { US(A), Qb, nullptr, nullptr, P + 3*262144, nullptr, 512,512,512, 512,512,512, 0,0, 1,0 };
    ga.d[1] = { P,     Qb, nullptr, nullptr, P + 4*262144, nullptr, 1536,512,512, 512,512,512, 0,0, 0,0 };
    ga.d[2] = { US(h_prev), US(A), nullptr, Tm,       nullptr, nullptr, 256,512,512,  512,512,6144, 0,0, 1,1 };
    ga.d[3] = { US(h_prev), P,     nullptr, Tm + 512, nullptr, nullptr, 256,1536,512, 512,512,6144, 0,0, 1,0 };
    for (int s = 0; s < 3; ++s) {
        ga.d[4+s] = { combb + 512 + (size_t)s*512, US(ain_w + 262144), ain_b + 512,
                      nullptr, kvb + (size_t)s*262144, nullptr, 256,1024,512, 2048,512,1024, 0,0, 0,1 };
        ga.d[7+s] = { combb + 512 + (size_t)s*512, US(proj_w + 1024 + (size_t)s*512), nullptr,
                      projout, nullptr, nullptr, 256,512,512, 2048,2560,512, 0,2, 0,1 };
    }
    gemm_mfma<<<dim3(192, 10), 256, 0, stream>>>(ga, lpOff, ppOff);

    // ---- d5: T1b (k5..8) + U8 = bf16(A^8 h) ----
    for (int i = 0; i < 10; ++i) ga.d[i] = z0;
    ga.d[0] = { US(h_prev), P + 3*262144, nullptr, Tm + 4*512, nullptr, nullptr, 256,2048,512, 512,512,6144, 0,0, 1,0 };
    ga.d[1] = { US(h_prev), P + 6*262144, nullptr, nullptr, U8b, nullptr, 256,512,512, 512,512,512, 0,0, 1,0 };
    gemm_mfma<<<dim3(128, 2), 256, 0, stream>>>(ga, lpOff, ppOff);

    // ---- d6: T2a (k9: W=A), T2b (k10..12: W=A^2..A^4) ----
    for (int i = 0; i < 10; ++i) ga.d[i] = z0;
    ga.d[0] = { U8b, US(A), nullptr, Tm + 8*512, nullptr, nullptr, 256,512,512,  512,512,6144, 0,0, 0,1 };
    ga.d[1] = { U8b, P,     nullptr, Tm + 9*512, nullptr, nullptr, 256,1536,512, 512,512,6144, 0,0, 0,0 };
    gemm_mfma<<<dim3(96, 2), 256, 0, stream>>>(ga, lpOff, ppOff);

    // ---- d7: per-row hssm + q + projA-hssm ----
    pwh2_kernel<<<256, 256, 0, stream>>>(Tm, coeff, h_prev, delta, Bx, hssm, combb,
                                         Wqb, ain_b, P0b, qb, projout);

    // ---- d8: tail (attn + out-proj + P2 + final LN) ----
    tail_kernel<<<256, 256, 0, stream>>>(qb, kvb, aout_wb, aout_b, P2b, projout,
                                         proj_g, proj_bt, out);
    #undef US
}

// Round 17
// 230.195 us; speedup vs baseline: 1.1590x; 1.1476x over previous
//
#include <hip/hip_runtime.h>
#include <math.h>

#define DIM 512
#define NB 256
#define KMAX 12   // Taylor terms (powers A^1..A^12)

using bf16x8 = __attribute__((ext_vector_type(8))) short;
using f32x4  = __attribute__((ext_vector_type(4))) float;
using float4v = __attribute__((ext_vector_type(4))) float;
using ushort4v = __attribute__((ext_vector_type(4))) unsigned short;

__device__ __forceinline__ unsigned short f2b(float f) {
    union { float f; unsigned int u; } v; v.f = f;
    unsigned int r = v.u + 0x7fffu + ((v.u >> 16) & 1u);
    return (unsigned short)(r >> 16);
}
__device__ __forceinline__ float b2f(unsigned short u) {
    union { unsigned int u; float f; } v; v.u = ((unsigned int)u) << 16;
    return v.f;
}
__device__ __forceinline__ ushort4v f2b4(float4v v) {
    ushort4v o;
    o.x = f2b(v.x); o.y = f2b(v.y); o.z = f2b(v.z); o.w = f2b(v.w);
    return o;
}

__device__ __forceinline__ void block_reduce2(float& s, float& q, float* sb1, float* sb2)
{
    int tid = threadIdx.x;
    #pragma unroll
    for (int off = 32; off > 0; off >>= 1) {
        s += __shfl_down(s, off);
        q += __shfl_down(q, off);
    }
    if ((tid & 63) == 0) { sb1[tid >> 6] = s; sb2[tid >> 6] = q; }
    __syncthreads();
    s = sb1[0] + sb1[1] + sb1[2] + sb1[3];
    q = sb2[0] + sb2[1] + sb2[2] + sb2[3];
    __syncthreads();
}

// ---------------------------------------------------------------------------
// Batched bf16 MFMA GEMM, BK=128.  C[m,n]=sum_k X[m,k]W[n,k]+b.
// acc: 0=store, 1=Cf+=, 2=atomicAdd(Cf).  Ct: transposed dual-write.
// lp.lnd_y == blockIdx.y -> fused LN/GELU/delta branch.  K % 128 == 0.
// ---------------------------------------------------------------------------
struct GemmDesc {
    const unsigned short* X;
    const unsigned short* W;
    const float* bias;
    float* Cf;
    unsigned short* Cb;
    unsigned short* Ct;
    int M, N, K, ldX, ldW, ldC, tr_row0, acc;
};
struct GemmArgs { GemmDesc d[10]; };
struct LnParams {
    const float* pre; const float* g; const float* beta;
    const float* w2; const float* b2; float* delta; float* coeff;
    int lnd_y;
};

__global__ __launch_bounds__(256) void gemm_mfma(GemmArgs args, LnParams lp)
{
    __shared__ unsigned short lsA[2][8192];
    __shared__ unsigned short lsB[2][8192];
    __shared__ float sb1[4], sb2[4];

    if ((int)blockIdx.y == lp.lnd_y) {
        int b = blockIdx.x, tid = threadIdx.x;
        int i0 = tid, i1 = tid + 256;
        float x0 = lp.pre[(size_t)b * DIM + i0];
        float x1 = lp.pre[(size_t)b * DIM + i1];
        float s = x0 + x1, q = x0 * x0 + x1 * x1;
        block_reduce2(s, q, sb1, sb2);
        float mean = s * (1.f / DIM);
        float var  = q * (1.f / DIM) - mean * mean;
        float inv  = rsqrtf(var + 1e-5f);
        float y0 = (x0 - mean) * inv * lp.g[i0] + lp.beta[i0];
        float y1 = (x1 - mean) * inv * lp.g[i1] + lp.beta[i1];
        float h0 = 0.5f * y0 * (1.f + erff(y0 * 0.70710678118654752f));
        float h1 = 0.5f * y1 * (1.f + erff(y1 * 0.70710678118654752f));
        float p = h0 * lp.w2[i0] + h1 * lp.w2[i1];
        float dummy = 0.f;
        block_reduce2(p, dummy, sb1, sb2);
        if (tid == 0) {
            float z = p + lp.b2[0];
            float d = (z > 20.f) ? z : log1pf(expf(z));
            lp.delta[b] = d;
            float c = 1.f;
            lp.coeff[b] = 1.f;
            for (int k = 1; k <= KMAX; ++k) { c *= d / (float)k; lp.coeff[k * 256 + b] = c; }
        }
        return;
    }

    GemmDesc de = args.d[blockIdx.y];
    int tn = de.N >> 6;
    int tiles = (de.M >> 6) * tn;
    int t = blockIdx.x;
    if (t >= tiles) return;
    int m0 = (t / tn) << 6;
    int n0 = (t % tn) << 6;

    int tid = threadIdx.x;
    int w = tid >> 6;
    int l = tid & 63;
    int nkt = de.K >> 7;      // BK=128

    int srow = w * 16 + (l >> 2);
    int schk = l & 3;
    const unsigned short* gA = de.X + (size_t)(m0 + srow) * de.ldX + schk * 8;
    const unsigned short* gB = de.W + (size_t)(n0 + srow) * de.ldW + schk * 8;
    unsigned short* lA = &lsA[0][(w * 64 + l) * 8];
    unsigned short* lB = &lsB[0][(w * 64 + l) * 8];

#define STAGE(bufi, kt)                                                          \
    do {                                                                         \
        for (int hh = 0; hh < 4; ++hh) {                                         \
            __builtin_amdgcn_global_load_lds(                                    \
                (const __attribute__((address_space(1))) unsigned int*)(gA + (size_t)(kt) * 128 + hh * 32), \
                (__attribute__((address_space(3))) unsigned int*)(lA + (bufi) * 8192 + hh * 2048), 16, 0, 0); \
            __builtin_amdgcn_global_load_lds(                                    \
                (const __attribute__((address_space(1))) unsigned int*)(gB + (size_t)(kt) * 128 + hh * 32), \
                (__attribute__((address_space(3))) unsigned int*)(lB + (bufi) * 8192 + hh * 2048), 16, 0, 0); \
        }                                                                        \
    } while (0)

    int mbase = (w >> 1) * 32;
    int nbase = (w & 1) * 32;

    f32x4 acc[2][2];
    #pragma unroll
    for (int i = 0; i < 2; ++i)
        #pragma unroll
        for (int j = 0; j < 2; ++j)
            acc[i][j] = (f32x4){0.f, 0.f, 0.f, 0.f};

    int kg = l >> 4;
    int fr = l & 15;
    int aslot = (mbase * 4 + fr * 4 + kg) * 8;
    int bslot = (nbase * 4 + fr * 4 + kg) * 8;

    STAGE(0, 0);

    for (int kt = 0; kt < nkt; ++kt) {
        __syncthreads();
        if (kt + 1 < nkt) STAGE((kt + 1) & 1, kt + 1);

        const unsigned short* bufA = &lsA[kt & 1][0];
        const unsigned short* bufB = &lsB[kt & 1][0];
        #pragma unroll
        for (int h = 0; h < 4; ++h) {
            bf16x8 a0 = *(const bf16x8*)(bufA + h * 2048 + aslot);
            bf16x8 a1 = *(const bf16x8*)(bufA + h * 2048 + aslot + 512);
            bf16x8 b0 = *(const bf16x8*)(bufB + h * 2048 + bslot);
            bf16x8 b1 = *(const bf16x8*)(bufB + h * 2048 + bslot + 512);
            acc[0][0] = __builtin_amdgcn_mfma_f32_16x16x32_bf16(a0, b0, acc[0][0], 0, 0, 0);
            acc[0][1] = __builtin_amdgcn_mfma_f32_16x16x32_bf16(a0, b1, acc[0][1], 0, 0, 0);
            acc[1][0] = __builtin_amdgcn_mfma_f32_16x16x32_bf16(a1, b0, acc[1][0], 0, 0, 0);
            acc[1][1] = __builtin_amdgcn_mfma_f32_16x16x32_bf16(a1, b1, acc[1][1], 0, 0, 0);
        }
    }

    #pragma unroll
    for (int mi = 0; mi < 2; ++mi) {
        #pragma unroll
        for (int ni = 0; ni < 2; ++ni) {
            int col = n0 + nbase + ni * 16 + fr;
            float bv = de.bias ? de.bias[col] : 0.f;
            #pragma unroll
            for (int r = 0; r < 4; ++r) {
                int row = m0 + mbase + mi * 16 + (l >> 4) * 4 + r;
                float v = acc[mi][ni][r] + bv;
                if (de.Cf) {
                    if (de.acc == 2)      atomicAdd(&de.Cf[(size_t)row * de.ldC + col], v);
                    else if (de.acc == 1) de.Cf[(size_t)row * de.ldC + col] += v;
                    else                  de.Cf[(size_t)row * de.ldC + col] = v;
                } else {
                    de.Cb[(size_t)row * de.ldC + col] = f2b(v);
                }
                if (de.Ct && row >= de.tr_row0)
                    de.Ct[(size_t)col * 512 + (row - de.tr_row0)] = f2b(v);
            }
        }
    }
#undef STAGE
}

// ---------------------------------------------------------------------------
// Unified prep: 14 convert segments + A^T transpose + gates zero-init.
// Grid 2432 x 256.
// ---------------------------------------------------------------------------
#define NSEG 14
struct PrepArgs {
    const float* sA[NSEG]; const float* sB[NSEG]; unsigned short* dst[NSEG];
    int n4[NSEG], dRL4[NSEG], sRLA4[NSEG], sRLB4[NSEG], half4[NSEG], offA[NSEG];
    const float* A; unsigned short* ATb;
    float* gates_zero; int gz_n4;
};
__global__ __launch_bounds__(256) void prep_kernel(PrepArgs a)
{
    __shared__ float tile[32][33];
    int bid = blockIdx.x, tid = threadIdx.x;
    if (bid < 2048) {
        const int gstride = 2048 * 256;
        int g0 = bid * 256 + tid;
        for (int seg = 0; seg < NSEG; ++seg) {
            int n4 = a.n4[seg];
            const float* sA = a.sA[seg];
            const float* sB = a.sB[seg];
            unsigned short* d = a.dst[seg];
            int dRL4 = a.dRL4[seg], sRLA4 = a.sRLA4[seg], sRLB4 = a.sRLB4[seg];
            int half4 = a.half4[seg], offA = a.offA[seg];
            for (int i = g0; i < n4; i += gstride) {
                int r = i / dRL4, c = i - r * dRL4;
                const float* src = (c < half4)
                    ? sA + ((size_t)r * sRLA4 + offA + c) * 4
                    : sB + ((size_t)r * sRLB4 + (c - half4)) * 4;
                float4v v = *(const float4v*)src;
                *(ushort4v*)(d + (size_t)i * 4) = f2b4(v);
            }
        }
    } else if (bid < 2304) {
        int tt = bid - 2048;
        int bx = tt & 15, by = tt >> 4;
        int tx = tid & 31, ty = tid >> 5;
        #pragma unroll
        for (int i = 0; i < 32; i += 8)
            tile[ty + i][tx] = a.A[(size_t)(by * 32 + ty + i) * 512 + bx * 32 + tx];
        __syncthreads();
        #pragma unroll
        for (int i = 0; i < 32; i += 8)
            a.ATb[(size_t)(bx * 32 + ty + i) * 512 + by * 32 + tx] = f2b(tile[tx][ty + i]);
    } else {
        // zero gates (for split-K atomic accumulation)
        float4v* gz = (float4v*)a.gates_zero;
        int g0 = (bid - 2304) * 256 + tid;
        const int gstride = 128 * 256;
        float4v z = (float4v){0.f, 0.f, 0.f, 0.f};
        for (int i = g0; i < a.gz_n4; i += gstride) gz[i] = z;
    }
}

// ---------------------------------------------------------------------------
// Fused pointwise: Taylor accum (K=12) + LSTM cell + projout bias-seed.
// combb (256 x 2048): [hssm | h_new s=0..2]
// Grid 640 x 256 (f4 work: 32768 taylor + 98304 lstm + 32768 projseed).
// ---------------------------------------------------------------------------
__global__ void pointwise_fused(
    const float* __restrict__ Tm, const float* __restrict__ coeff,
    const float* __restrict__ h_prev, const float* __restrict__ delta,
    const float* __restrict__ Bx, float* __restrict__ hssm,
    unsigned short* __restrict__ combb,
    const float* __restrict__ gates, const float* __restrict__ bih,
    const float* __restrict__ bhh, const float* __restrict__ cin,
    const float* __restrict__ decays,
    float* __restrict__ hout, float* __restrict__ cout,
    const float* __restrict__ proj_b, float* __restrict__ projout)
{
    int idx4 = blockIdx.x * 256 + threadIdx.x;
    int base = idx4 * 4;
    if (base < 131072) {
        int b = base >> 9, i = base & 511;
        const float* Tr = Tm + (size_t)b * (KMAX * DIM) + i;
        float4v a = *(const float4v*)(h_prev + base);
        #pragma unroll
        for (int k = 1; k <= KMAX; ++k) {
            float c = coeff[k * 256 + b];
            float4v t = *(const float4v*)(Tr + (size_t)(k - 1) * DIM);
            a.x += c * t.x; a.y += c * t.y; a.z += c * t.z; a.w += c * t.w;
        }
        float dl = delta[b];
        float4v bx = *(const float4v*)(Bx + base);
        a.x += dl * bx.x; a.y += dl * bx.y; a.z += dl * bx.z; a.w += dl * bx.w;
        *(float4v*)(hssm + base) = a;
        *(ushort4v*)(combb + (size_t)b * 2048 + i) = f2b4(a);
    } else if (base < 524288) {
        int i2 = base - 131072;
        int s = i2 / (NB * DIM);
        int r = i2 - s * (NB * DIM);
        int b = r >> 9, d = r & 511;
        const float* gr = gates + (size_t)s * 524288 + (size_t)b * 2048 + d;
        const float* bi = bih + s * 2048 + d;
        const float* bh = bhh + s * 2048 + d;
        float4v gi = *(const float4v*)(gr);
        float4v gf = *(const float4v*)(gr + 512);
        float4v gg = *(const float4v*)(gr + 1024);
        float4v go = *(const float4v*)(gr + 1536);
        float4v bi0 = *(const float4v*)(bi),        bh0 = *(const float4v*)(bh);
        float4v bi1 = *(const float4v*)(bi + 512),  bh1 = *(const float4v*)(bh + 512);
        float4v bi2 = *(const float4v*)(bi + 1024), bh2 = *(const float4v*)(bh + 1024);
        float4v bi3 = *(const float4v*)(bi + 1536), bh3 = *(const float4v*)(bh + 1536);
        float4v c = *(const float4v*)(cin + i2);
        float dec = decays[s];
        float4v hn, cn;
        #pragma unroll
        for (int j = 0; j < 4; ++j) {
            float vgi = ((const float*)&gi)[j] + ((const float*)&bi0)[j] + ((const float*)&bh0)[j];
            float vgf = ((const float*)&gf)[j] + ((const float*)&bi1)[j] + ((const float*)&bh1)[j];
            float vgg = ((const float*)&gg)[j] + ((const float*)&bi2)[j] + ((const float*)&bh2)[j];
            float vgo = ((const float*)&go)[j] + ((const float*)&bi3)[j] + ((const float*)&bh3)[j];
            float ig = 1.f / (1.f + expf(-vgi));
            float fg = 1.f / (1.f + expf(-vgf));
            float g_ = tanhf(vgg);
            float og = 1.f / (1.f + expf(-vgo));
            float cc = ((const float*)&c)[j];
            float craw = fg * cc + ig * g_;
            ((float*)&hn)[j] = og * tanhf(craw);
            ((float*)&cn)[j] = dec * cc + (1.f - dec) * craw;
        }
        *(float4v*)(hout + i2) = hn;
        *(float4v*)(cout + i2) = cn;
        *(ushort4v*)(combb + (size_t)b * 2048 + 512 + s * 512 + d) = f2b4(hn);
    } else {
        // seed projout[b, :] = proj_b[:]  (split-K projA atomically accumulates)
        int i = idx4 - 131072;          // 0..32767 f4 units
        int c4 = i & 127;
        float4v pb = *(const float4v*)(proj_b + c4 * 4);
        *(float4v*)(projout + (size_t)i * 4) = pb;
    }
}

// ---------------------------------------------------------------------------
// Fused tail: attn softmax + fused = ctx.aout_w^T + aout_b
//           + out = LN(projA + fused.P2^T).  One block per row b.
// ---------------------------------------------------------------------------
__global__ __launch_bounds__(256) void tail_kernel(
    const unsigned short* __restrict__ qb, const unsigned short* __restrict__ kvb,
    const unsigned short* __restrict__ aout_wb, const float* __restrict__ aout_b,
    const unsigned short* __restrict__ P2b, const float* __restrict__ projA,
    const float* __restrict__ fin_g, const float* __restrict__ fin_beta,
    float* __restrict__ outp)
{
    __shared__ float ctxs[512];
    __shared__ float fusedl[512];
    __shared__ float totals[512];
    __shared__ float sb1[4], sb2[4];
    int b = blockIdx.x, tid = threadIdx.x;

    if (tid < 128) {
        int h = tid >> 4, sub = (tid & 15) * 4;
        int col = h * 64 + sub;
        ushort4v q4 = *(const ushort4v*)(qb + (size_t)b * 512 + col);
        float qf[4] = { b2f(q4.x), b2f(q4.y), b2f(q4.z), b2f(q4.w) };
        float p[3];
        ushort4v k4[3], v4[3];
        #pragma unroll
        for (int s = 0; s < 3; ++s) {
            k4[s] = *(const ushort4v*)(kvb + (size_t)s * 262144 + (size_t)b * 1024 + col);
            v4[s] = *(const ushort4v*)(kvb + (size_t)s * 262144 + (size_t)b * 1024 + 512 + col);
            p[s] = qf[0] * b2f(k4[s].x) + qf[1] * b2f(k4[s].y)
                 + qf[2] * b2f(k4[s].z) + qf[3] * b2f(k4[s].w);
        }
        #pragma unroll
        for (int off = 1; off < 16; off <<= 1) {
            p[0] += __shfl_xor(p[0], off);
            p[1] += __shfl_xor(p[1], off);
            p[2] += __shfl_xor(p[2], off);
        }
        const float scale = 0.125f;
        float p0 = p[0] * scale, p1 = p[1] * scale, p2 = p[2] * scale;
        float m = fmaxf(p0, fmaxf(p1, p2));
        float w0 = expf(p0 - m), w1 = expf(p1 - m), w2 = expf(p2 - m);
        float invs = 1.f / (w0 + w1 + w2);
        ctxs[col + 0] = (w0 * b2f(v4[0].x) + w1 * b2f(v4[1].x) + w2 * b2f(v4[2].x)) * invs;
        ctxs[col + 1] = (w0 * b2f(v4[0].y) + w1 * b2f(v4[1].y) + w2 * b2f(v4[2].y)) * invs;
        ctxs[col + 2] = (w0 * b2f(v4[0].z) + w1 * b2f(v4[1].z) + w2 * b2f(v4[2].z)) * invs;
        ctxs[col + 3] = (w0 * b2f(v4[0].w) + w1 * b2f(v4[1].w) + w2 * b2f(v4[2].w)) * invs;
    }
    __syncthreads();

    for (int jj = tid; jj < 512; jj += 256) {
        float acc = aout_b[jj];
        const unsigned short* wr = aout_wb + (size_t)jj * 512;
        for (int k = 0; k < 512; k += 8) {
            ushort4v w0 = *(const ushort4v*)(wr + k);
            ushort4v w1 = *(const ushort4v*)(wr + k + 4);
            acc += ctxs[k+0]*b2f(w0.x) + ctxs[k+1]*b2f(w0.y)
                 + ctxs[k+2]*b2f(w0.z) + ctxs[k+3]*b2f(w0.w)
                 + ctxs[k+4]*b2f(w1.x) + ctxs[k+5]*b2f(w1.y)
                 + ctxs[k+6]*b2f(w1.z) + ctxs[k+7]*b2f(w1.w);
        }
        fusedl[jj] = acc;
    }
    __syncthreads();

    for (int ii = tid; ii < 512; ii += 256) {
        float acc = projA[(size_t)b * 512 + ii];
        const unsigned short* pr = P2b + (size_t)ii * 512;
        for (int j = 0; j < 512; j += 8) {
            ushort4v w0 = *(const ushort4v*)(pr + j);
            ushort4v w1 = *(const ushort4v*)(pr + j + 4);
            acc += fusedl[j+0]*b2f(w0.x) + fusedl[j+1]*b2f(w0.y)
                 + fusedl[j+2]*b2f(w0.z) + fusedl[j+3]*b2f(w0.w)
                 + fusedl[j+4]*b2f(w1.x) + fusedl[j+5]*b2f(w1.y)
                 + fusedl[j+6]*b2f(w1.z) + fusedl[j+7]*b2f(w1.w);
        }
        totals[ii] = acc;
    }
    __syncthreads();

    float x0 = totals[tid], x1 = totals[tid + 256];
    float s = x0 + x1, q = x0 * x0 + x1 * x1;
    block_reduce2(s, q, sb1, sb2);
    float mean = s * (1.f / DIM);
    float var  = q * (1.f / DIM) - mean * mean;
    float inv  = rsqrtf(var + 1e-5f);
    outp[(size_t)b * DIM + tid]       = (x0 - mean) * inv * fin_g[tid]       + fin_beta[tid];
    outp[(size_t)b * DIM + tid + 256] = (x1 - mean) * inv * fin_g[tid + 256] + fin_beta[tid + 256];
}

// ---------------------------------------------------------------------------
extern "C" void kernel_launch(void* const* d_in, const int* in_sizes, int n_in,
                              void* d_out, int out_size, void* d_ws, size_t ws_size,
                              hipStream_t stream)
{
    const float* x        = (const float*)d_in[0];
    const float* h_prev   = (const float*)d_in[1];
    const float* lstm_h   = (const float*)d_in[2];
    const float* lstm_c   = (const float*)d_in[3];
    const float* A        = (const float*)d_in[4];
    const float* Bm       = (const float*)d_in[5];
    const float* dn_w1    = (const float*)d_in[6];
    const float* dn_b1    = (const float*)d_in[7];
    const float* dn_g     = (const float*)d_in[8];
    const float* dn_beta  = (const float*)d_in[9];
    const float* dn_w2    = (const float*)d_in[10];
    const float* dn_b2    = (const float*)d_in[11];
    const float* wih      = (const float*)d_in[12];
    const float* whh      = (const float*)d_in[13];
    const float* bih      = (const float*)d_in[14];
    const float* bhh      = (const float*)d_in[15];
    const float* decays   = (const float*)d_in[16];
    const float* ain_w    = (const float*)d_in[17];
    const float* ain_b    = (const float*)d_in[18];
    const float* aout_w   = (const float*)d_in[19];
    const float* aout_b   = (const float*)d_in[20];
    const float* proj_w   = (const float*)d_in[21];
    const float* proj_b   = (const float*)d_in[22];
    const float* proj_g   = (const float*)d_in[23];
    const float* proj_bt  = (const float*)d_in[24];

    float* out  = (float*)d_out;
    float* hssm = out + 131072;
    float* hnew = out + 262144;
    float* cnew = out + 655360;

    // ---- workspace (bf16 section) ----
    unsigned short* us = (unsigned short*)d_ws;
    unsigned short* hpb     = us;                  // 131072
    unsigned short* ATb     = us + 131072;         // 262144
    unsigned short* dn_w1b  = us + 393216;         // 262144
    unsigned short* Bmb     = us + 655360;         // 262144
    unsigned short* ain_wb  = us + 917504;         // 786432
    unsigned short* proj_wb = us + 1703936;        // 1048576 (512x2048 packed [P0|P1])
    unsigned short* P2b     = us + 2752512;        // 262144
    unsigned short* aout_wb = us + 3014656;        // 262144
    unsigned short* Pw      = us + 3276800;        // 8*262144 [A^1..A^8]
    unsigned short* Qa      = us + 5373952;        // 262144
    unsigned short* Qb      = us + 5636096;        // 262144
    unsigned short* Wcat    = us + 5898240;        // 6291456
    unsigned short* Xcat    = us + 12189696;       // 786432
    unsigned short* combb   = us + 12976128;       // 524288 (256x2048) [hssm|hnew*3]
    unsigned short* qb      = us + 13500416;       // 131072
    unsigned short* kvb     = us + 13631488;       // 786432
    unsigned short* U8b     = us + 14417920;       // 131072 (bf16 A^8 h)
    // ---- fp32 section ----
    float* fbase  = (float*)(us + 14548992);
    float* pre1   = fbase;                         // 131072 (reused as projout)
    float* delta  = fbase + 131072;                // 256
    float* coeff  = fbase + 131328;                // 13*256
    float* Bx     = fbase + 134656;                // 131072
    float* Tm     = fbase + 265728;                // 256*6144
    float* gates  = fbase + 1838592;               // 1572864
    float* projout = pre1;

    LnParams lpOff; lpOff.pre = nullptr; lpOff.g = nullptr; lpOff.beta = nullptr;
    lpOff.w2 = nullptr; lpOff.b2 = nullptr; lpOff.delta = nullptr; lpOff.coeff = nullptr;
    lpOff.lnd_y = -1;

    // ---- 1. unified prep (14 segments + A^T + gates zero) ----
    PrepArgs pa;
    int sidx = 0;
    auto LIN = [&](const float* s, unsigned short* d, int n4) {
        pa.sA[sidx]=s; pa.sB[sidx]=s; pa.dst[sidx]=d; pa.n4[sidx]=n4;
        pa.dRL4[sidx]=n4; pa.sRLA4[sidx]=0; pa.sRLB4[sidx]=0;
        pa.half4[sidx]=n4; pa.offA[sidx]=0; ++sidx;
    };
    LIN(h_prev, hpb,     32768);
    LIN(A,      Pw,      65536);
    LIN(dn_w1,  dn_w1b,  65536);
    LIN(Bm,     Bmb,     65536);
    LIN(ain_w,  ain_wb,  196608);
    LIN(aout_w, aout_wb, 65536);
    pa.sA[sidx]=proj_w; pa.sB[sidx]=proj_w + 1024; pa.dst[sidx]=proj_wb; pa.n4[sidx]=262144;
    pa.dRL4[sidx]=512; pa.sRLA4[sidx]=640; pa.sRLB4[sidx]=640; pa.half4[sidx]=128; pa.offA[sidx]=0; ++sidx;
    pa.sA[sidx]=proj_w; pa.sB[sidx]=proj_w; pa.dst[sidx]=P2b; pa.n4[sidx]=65536;
    pa.dRL4[sidx]=128; pa.sRLA4[sidx]=640; pa.sRLB4[sidx]=640; pa.half4[sidx]=128; pa.offA[sidx]=128; ++sidx;
    for (int s = 0; s < 3; ++s) {
        pa.sA[sidx]=wih + (size_t)s*1048576; pa.sB[sidx]=whh + (size_t)s*1048576;
        pa.dst[sidx]=Wcat + (size_t)s*2097152; pa.n4[sidx]=524288;
        pa.dRL4[sidx]=256; pa.sRLA4[sidx]=128; pa.sRLB4[sidx]=128; pa.half4[sidx]=128; pa.offA[sidx]=0; ++sidx;
    }
    for (int s = 0; s < 3; ++s) {
        pa.sA[sidx]=x; pa.sB[sidx]=lstm_h + (size_t)s*131072;
        pa.dst[sidx]=Xcat + (size_t)s*262144; pa.n4[sidx]=65536;
        pa.dRL4[sidx]=256; pa.sRLA4[sidx]=128; pa.sRLB4[sidx]=128; pa.half4[sidx]=128; pa.offA[sidx]=0; ++sidx;
    }
    pa.A = A; pa.ATb = ATb;
    pa.gates_zero = gates; pa.gz_n4 = 393216;
    prep_kernel<<<2432, 256, 0, stream>>>(pa);

    GemmArgs ga;
    // ---- 2. batch1: dense1, Bx, G1 (A^2 + Q2), LSTM x3 split-K x2 (atomic) ----
    ga.d[0] = { Xcat, dn_w1b, dn_b1, pre1, nullptr, nullptr, 256, 512, 512, 1024, 512, 512, 0, 0 };
    ga.d[1] = { Xcat, Bmb,    nullptr, Bx,  nullptr, nullptr, 256, 512, 512, 1024, 512, 512, 0, 0 };
    ga.d[2] = { Pw, ATb, nullptr, nullptr, Pw + 1*262144, Qa, 512, 512, 512, 512, 512, 512, 0, 0 };
    for (int s = 0; s < 3; ++s)
        for (int half = 0; half < 2; ++half)
            ga.d[3 + s * 2 + half] = { Xcat + (size_t)s * 262144 + half * 512,
                                       Wcat + (size_t)s * 2097152 + half * 512, nullptr,
                                       gates + (size_t)s * 524288, nullptr, nullptr,
                                       256, 2048, 512, 1024, 1024, 2048, 0, 2 };
    gemm_mfma<<<dim3(128, 9), 256, 0, stream>>>(ga, lpOff);

    // ---- 3. G2 [A^3,A^4]+Q4  +  fused LN/GELU/delta (y==1) ----
    LnParams lp1 = { pre1, dn_g, dn_beta, dn_w2, dn_b2, delta, coeff, 1 };
    ga.d[0] = { Pw, Qa, nullptr, nullptr, Pw + 2*262144, Qb, 1024, 512, 512, 512, 512, 512, 512, 0 };
    gemm_mfma<<<dim3(256, 2), 256, 0, stream>>>(ga, lp1);

    // ---- 4. G3 [A^5..A^8] ----
    ga.d[0] = { Pw, Qb, nullptr, nullptr, Pw + 4*262144, nullptr, 2048, 512, 512, 512, 512, 512, 0, 0 };
    gemm_mfma<<<dim3(256, 1), 256, 0, stream>>>(ga, lpOff);

    // ---- 5. Taylor1 (k=1..8, N=4096) + U8 = bf16(A^8 h) ----
    ga.d[0] = { hpb, Pw, nullptr, Tm, nullptr, nullptr, 256, 4096, 512, 512, 512, 6144, 0, 0 };
    ga.d[1] = { hpb, Pw + 7*262144, nullptr, nullptr, U8b, nullptr, 256, 512, 512, 512, 512, 512, 0, 0 };
    gemm_mfma<<<dim3(256, 2), 256, 0, stream>>>(ga, lpOff);

    // ---- 6. Taylor2: T[k=9..12] = (A^j)(A^8 h), j=1..4 ----
    ga.d[0] = { U8b, Pw, nullptr, Tm + 4096, nullptr, nullptr, 256, 2048, 512, 512, 512, 6144, 0, 0 };
    gemm_mfma<<<dim3(128, 1), 256, 0, stream>>>(ga, lpOff);

    // ---- 7. fused pointwise (taylor accum + lstm cell + projout seed) ----
    pointwise_fused<<<640, 256, 0, stream>>>(Tm, coeff, h_prev, delta, Bx, hssm, combb,
                                             gates, bih, bhh, lstm_c, decays, hnew, cnew,
                                             proj_b, projout);

    // ---- 8. q + kv x3 + projA split-K x4 (atomic into seeded projout) ----
    ga.d[0] = { combb, ain_wb, ain_b, nullptr, qb, nullptr, 256, 512, 512, 2048, 512, 512, 0, 0 };
    for (int s = 0; s < 3; ++s)
        ga.d[1 + s] = { combb + 512 + (size_t)s * 512, ain_wb + 262144, ain_b + 512,
                        nullptr, kvb + (size_t)s * 262144, nullptr, 256, 1024, 512, 2048, 512, 1024, 0, 0 };
    for (int ks = 0; ks < 4; ++ks)
        ga.d[4 + ks] = { combb + ks * 512, proj_wb + ks * 512, nullptr, projout, nullptr, nullptr,
                         256, 512, 512, 2048, 2048, 512, 0, 2 };
    gemm_mfma<<<dim3(64, 8), 256, 0, stream>>>(ga, lpOff);

    // ---- 9. fused tail: attn + out-proj + P2 + final LN ----
    tail_kernel<<<256, 256, 0, stream>>>(qb, kvb, aout_wb, aout_b, P2b, projout,
                                         proj_g, proj_bt, out);
}